// Round 11
// baseline (1556.545 us; speedup 1.0000x reference)
//
#include <hip/hip_runtime.h>

#define DIM 512
#define NROWS 131072

typedef __attribute__((ext_vector_type(8))) __bf16 bf16x8;
typedef __attribute__((ext_vector_type(4))) float f32x4;

__device__ __forceinline__ unsigned short f2bf(float f) {
  unsigned u = __builtin_bit_cast(unsigned, f);
  return (unsigned short)((u + 0x7FFFu + ((u >> 16) & 1u)) >> 16);
}
__device__ __forceinline__ float bf2f(unsigned short u) {
  return __builtin_bit_cast(float, (unsigned)u << 16);
}
__device__ __forceinline__ f32x4 mfma16(bf16x8 a, bf16x8 b, f32x4 c) {
  return __builtin_amdgcn_mfma_f32_16x16x32_bf16(a, b, c, 0, 0, 0);
}
__device__ __forceinline__ float sigmoid_fast(float v) {
  return 1.0f / (1.0f + __expf(-v));
}
__device__ __forceinline__ float tanh_fast(float v) {
  float e = __expf(2.0f * v);
  return 1.0f - 2.0f / (e + 1.0f);
}
__device__ __forceinline__ void gl2lds(const void* g, void* l) {
  __builtin_amdgcn_global_load_lds(
      (const __attribute__((address_space(1))) unsigned int*)g,
      (__attribute__((address_space(3))) unsigned int*)l, 16, 0, 0);
}

// ---------------------------------------------------------------------------
// Weight pre-pack: fp32 W[out=512][in=512] -> bf16 B-fragments.
// Frag (gate g, kstep f, colfrag c): lane l holds 8 bf16 =
//   W[c*16 + (l&15)][f*32 + (l>>4)*8 + 0..7]
// elem index = ((g*16+f)*32 + c)*512 + l*8 + e.  Gates: rx,zx,rh,zh,nx,nh.
// ---------------------------------------------------------------------------
__global__ void prepack_weights(const float* __restrict__ W0, const float* __restrict__ W1,
                                const float* __restrict__ W2, const float* __restrict__ W3,
                                const float* __restrict__ W4, const float* __restrict__ W5,
                                unsigned short* __restrict__ out) {
  int idx = blockIdx.x * 256 + threadIdx.x;
  int e = idx & 7;
  int l = (idx >> 3) & 63;
  int c = (idx >> 9) & 31;
  int f = (idx >> 14) & 15;
  int g = idx >> 18;
  const float* W = (g == 0) ? W0 : (g == 1) ? W1 : (g == 2) ? W2
                 : (g == 3) ? W3 : (g == 4) ? W4 : W5;
  int row = c * 16 + (l & 15);
  int kk  = f * 32 + ((l >> 4) << 3) + e;
  out[idx] = f2bf(W[row * DIM + kk]);
}

// fp32 -> bf16 row-major copy (x and h)
__global__ void prep_bf16(const float* __restrict__ in, unsigned short* __restrict__ ob) {
  size_t i = (size_t)(blockIdx.x * 256 + threadIdx.x) * 8;
  float4 a0 = *(const float4*)(in + i);
  float4 a1 = *(const float4*)(in + i + 4);
  union { unsigned short us[8]; uint4 v; } p;
  p.us[0] = f2bf(a0.x); p.us[1] = f2bf(a0.y); p.us[2] = f2bf(a0.z); p.us[3] = f2bf(a0.w);
  p.us[4] = f2bf(a1.x); p.us[5] = f2bf(a1.y); p.us[6] = f2bf(a1.z); p.us[7] = f2bf(a1.w);
  *(uint4*)(ob + i) = p.v;
}

// ===========================================================================
// Main: fused 3-sweep GRU, 2 independent blocks/CU.
// Block = 64r x 512c, 256 thr (4 waves), wave = 64r x 128c, 32 MFMA/window.
// LDS = B double-buffer only (2 x 32KB).  A-fragments: direct global->reg
// from bf16 xb / hb / rhb.  Sweeps: Z {zx,zh} -> z (bf16 ws or fp32 d_out);
// R {rx,rh} -> rh = sigmoid(r)*h -> rhb; N {nx,nh} -> combine.
// Window (R5-proven): [A-loads; stage-8 gl2lds for next; vmcnt(8); barrier;
// ds_read B-frags; 32 MFMA; barrier].  Sweeps chain B-chunks (v31 stages the
// next sweep's first chunk).
// ===========================================================================
__global__ __launch_bounds__(256, 2)
void gru_3sweep(const float* __restrict__ h,
                const unsigned short* __restrict__ xb,
                const unsigned short* __restrict__ hb,
                unsigned short* __restrict__ rhb,
                unsigned short* __restrict__ zb,     // bf16 z stage (may be null)
                const unsigned char* __restrict__ WB,
                const float* __restrict__ b_rx, const float* __restrict__ b_rh,
                const float* __restrict__ b_zx, const float* __restrict__ b_zh,
                const float* __restrict__ b_nx, const float* __restrict__ b_nh,
                float* __restrict__ out) {
  __shared__ __align__(1024) unsigned char lds[65536];

  const int tid  = threadIdx.x;
  const int lane = tid & 63;
  const int w    = tid >> 6;            // 0..3 (col group of 128)
  const int bid  = blockIdx.x;
  const int swz  = (bid & 7) * 256 + (bid >> 3);   // XCD-bijective (2048%8==0)
  const int row0 = swz * 64;
  const int lr   = lane & 15;
  const int lk   = lane >> 4;

  f32x4 acc[4][8];
  bf16x8 af[4], bfr[8];

  auto stageB = [&](int g, int f, int buf) {       // 32KB chunk, 8 gl2lds
    const unsigned char* src = WB + (size_t)(g * 16 + f) * 32768;
#pragma unroll
    for (int it = 0; it < 8; ++it) {
      int o = (it * 256 + tid) * 16;
      gl2lds(src + o, &lds[buf * 32768 + o]);
    }
  };
  auto loadAf = [&](const unsigned short* base, int f) {
#pragma unroll
    for (int rf = 0; rf < 4; ++rf)
      af[rf] = *(const bf16x8*)(base + (size_t)(row0 + rf * 16 + lr) * DIM
                                + f * 32 + lk * 8);
  };
  auto readB = [&](int buf) {
#pragma unroll
    for (int cf = 0; cf < 8; ++cf)
      bfr[cf] = *(const bf16x8*)&lds[buf * 32768 + (w * 8 + cf) * 1024 + lane * 16];
  };

#define MFMA32()                                                               \
  do {                                                                         \
    __builtin_amdgcn_s_setprio(1);                                             \
    _Pragma("unroll")                                                          \
    for (int rf_ = 0; rf_ < 4; ++rf_)                                          \
      _Pragma("unroll")                                                        \
      for (int cf_ = 0; cf_ < 8; ++cf_)                                        \
        acc[rf_][cf_] = mfma16(af[rf_], bfr[cf_], acc[rf_][cf_]);              \
    __builtin_amdgcn_s_setprio(0);                                             \
  } while (0)

  // v even (x-window) reads buf0; v odd (h-window) reads buf1.
#define SWEEP(GX, GH, HSRC, NEXTG, HAVE_NEXT)                                  \
  {                                                                            \
    _Pragma("unroll")                                                          \
    for (int rf_ = 0; rf_ < 4; ++rf_)                                          \
      _Pragma("unroll")                                                        \
      for (int cf_ = 0; cf_ < 8; ++cf_)                                        \
        acc[rf_][cf_] = (f32x4){0.f, 0.f, 0.f, 0.f};                           \
    _Pragma("unroll 1")                                                        \
    for (int f = 0; f < 16; ++f) {                                             \
      /* x-window: gate GX(f) @ buf0; stage GH(f) -> buf1 */                   \
      loadAf(xb, f);                                                           \
      stageB((GH), f, 1);                                                      \
      asm volatile("s_waitcnt vmcnt(8)" ::: "memory");                         \
      __builtin_amdgcn_s_barrier();                                            \
      readB(0);                                                                \
      MFMA32();                                                                \
      __builtin_amdgcn_s_barrier();                                            \
      /* h-window: gate GH(f) @ buf1; stage GX(f+1)|next-sweep -> buf0 */      \
      loadAf((HSRC), f);                                                       \
      if (f < 15)            stageB((GX), f + 1, 0);                           \
      else if (HAVE_NEXT)    stageB((NEXTG), 0, 0);                            \
      if (f < 15 || HAVE_NEXT)                                                 \
        asm volatile("s_waitcnt vmcnt(8)" ::: "memory");                       \
      else                                                                     \
        asm volatile("s_waitcnt vmcnt(0)" ::: "memory");                       \
      __builtin_amdgcn_s_barrier();                                            \
      readB(1);                                                                \
      MFMA32();                                                                \
      __builtin_amdgcn_s_barrier();                                            \
    }                                                                          \
  }

  // ---- prologue: stage zx(0) -> buf0 ----
  stageB(1, 0, 0);

  // ================= sweep Z: z = sigmoid(x@Wzx + h@Wzh + b) ================
  SWEEP(1, 3, hb, 0, true);            // v31 stages rx(0) -> buf0
#pragma unroll
  for (int cf = 0; cf < 8; ++cf) {
    const int col = (w * 8 + cf) * 16 + lr;
    const float bz = b_zx[col] + b_zh[col];
#pragma unroll
    for (int rf = 0; rf < 4; ++rf)
#pragma unroll
      for (int j = 0; j < 4; ++j) {
        const size_t off = (size_t)(row0 + rf * 16 + lk * 4 + j) * DIM + col;
        const float zv = sigmoid_fast(acc[rf][cf][j] + bz);
        if (zb) zb[off] = f2bf(zv); else out[off] = zv;
      }
  }

  // ====== sweep R: r = sigmoid(x@Wrx + h@Wrh + b); rh = r*h -> rhb =========
  SWEEP(0, 2, hb, 4, true);            // v31 stages nx(0) -> buf0
#pragma unroll
  for (int cf = 0; cf < 8; ++cf) {
    const int col = (w * 8 + cf) * 16 + lr;
    const float bs = b_rx[col] + b_rh[col];
#pragma unroll
    for (int rf = 0; rf < 4; ++rf)
#pragma unroll
      for (int j = 0; j < 4; ++j) {
        const size_t off = (size_t)(row0 + rf * 16 + lk * 4 + j) * DIM + col;
        const float rv = sigmoid_fast(acc[rf][cf][j] + bs);
        rhb[off] = f2bf(rv * bf2f(hb[off]));
      }
  }
  __syncthreads();                     // rhb stores drained + all waves past

  // ======== sweep N: n = tanh(x@Wnx + rh@Wnh + b); combine epilogue ========
  SWEEP(4, 5, rhb, 0, false);
#pragma unroll
  for (int cf = 0; cf < 8; ++cf) {
    const int col = (w * 8 + cf) * 16 + lr;
    const float bn = b_nx[col] + b_nh[col];
#pragma unroll
    for (int rf = 0; rf < 4; ++rf)
#pragma unroll
      for (int j = 0; j < 4; ++j) {
        const size_t off = (size_t)(row0 + rf * 16 + lk * 4 + j) * DIM + col;
        const float nv = tanh_fast(acc[rf][cf][j] + bn);
        const float zv = zb ? bf2f(zb[off]) : out[off];
        out[off] = (1.0f - zv) * nv + zv * h[off];
      }
  }
#undef SWEEP
#undef MFMA32
}

// ===========================================================================
// Fallback: round-5 kernel (671 us proven) for small workspaces.
// ===========================================================================
#define R5_BOFF 65536
#define R5_XOFF 131072
#define R5_LDS  147456

__global__ __launch_bounds__(512, 1)
void gru_fused_r5(const float* __restrict__ h,
                  const unsigned short* __restrict__ xb,
                  const unsigned char* __restrict__ WB,
                  const float* __restrict__ b_rx, const float* __restrict__ b_rh,
                  const float* __restrict__ b_zx, const float* __restrict__ b_zh,
                  const float* __restrict__ b_nx, const float* __restrict__ b_nh,
                  float* __restrict__ out) {
  __shared__ __align__(1024) unsigned char lds[R5_LDS];

  const int tid  = threadIdx.x;
  const int lane = tid & 63;
  const int w    = tid >> 6;
  const int cfg0 = w * 4;
  const int row0 = blockIdx.x * 64;
  const int lr   = lane & 15;
  const int lk   = lane >> 4;

  auto stageB = [&](int g, int f, int dst) {
    const unsigned char* src = WB + (size_t)(g * 16 + f) * 32768;
#pragma unroll
    for (int it = 0; it < 4; ++it) {
      int o = (it * 512 + tid) * 16;
      gl2lds(src + o, &lds[dst + o]);
    }
  };
  auto stageXpair = [&](int p) {
    int fh = tid >> 8, rf = (tid >> 6) & 3, l = tid & 63;
    const unsigned short* src = xb + (size_t)(row0 + rf * 16 + (l & 15)) * DIM
                                + p * 64 + fh * 32 + (l >> 4) * 8;
    gl2lds(src, &lds[R5_XOFF + (p & 1) * 8192 + tid * 16]);
  };
  auto gateStage = [&](int abase, int bbase, f32x4 (&A)[4][4]) {
    bf16x8 af[4], bfr[4];
#pragma unroll
    for (int rf = 0; rf < 4; ++rf)
      af[rf] = *(const bf16x8*)&lds[abase + rf * 1024 + lane * 16];
#pragma unroll
    for (int cf = 0; cf < 4; ++cf)
      bfr[cf] = *(const bf16x8*)&lds[bbase + (cfg0 + cf) * 1024 + lane * 16];
#pragma unroll
    for (int rf = 0; rf < 4; ++rf)
#pragma unroll
      for (int cf = 0; cf < 4; ++cf)
        A[rf][cf] = mfma16(af[rf], bfr[cf], A[rf][cf]);
  };

  f32x4 accR[4][4] = {}, accZ[4][4] = {};

#pragma unroll
  for (int it = 0; it < 16; ++it) {
    int i = tid + it * 512;
    int row = i >> 7;
    int k = (i & 127) * 4;
    float4 hv4 = *(const float4*)(h + (size_t)(row0 + row) * DIM + k);
    union { unsigned short us[4]; uint2 v; } p;
    p.us[0] = f2bf(hv4.x); p.us[1] = f2bf(hv4.y);
    p.us[2] = f2bf(hv4.z); p.us[3] = f2bf(hv4.w);
    *(uint2*)&lds[(k >> 5) * 4096 + (row >> 4) * 1024
                  + (((k >> 3) & 3) * 16 + (row & 15)) * 16 + (k & 4) * 2] = p.v;
  }
  stageXpair(0);
  stageB(0, 0, R5_BOFF);
  __syncthreads();

#pragma unroll 1
  for (int f = 0; f < 16; ++f) {
    const int xo = R5_XOFF + ((f >> 1) & 1) * 8192 + (f & 1) * 4096;
    const int ho = f * 4096;
    stageB(1, f, R5_BOFF + 32768);
    if (f & 1) {
      int p1 = (f >> 1) + 1; if (p1 > 7) p1 = 7;
      stageXpair(p1);
      asm volatile("s_waitcnt vmcnt(5)" ::: "memory");
    } else {
      asm volatile("s_waitcnt vmcnt(4)" ::: "memory");
    }
    __builtin_amdgcn_s_barrier();
    gateStage(xo, R5_BOFF, accR);
    __builtin_amdgcn_s_barrier();
    stageB(2, f, R5_BOFF);
    asm volatile("s_waitcnt vmcnt(4)" ::: "memory");
    __builtin_amdgcn_s_barrier();
    gateStage(xo, R5_BOFF + 32768, accZ);
    __builtin_amdgcn_s_barrier();
    stageB(3, f, R5_BOFF + 32768);
    asm volatile("s_waitcnt vmcnt(4)" ::: "memory");
    __builtin_amdgcn_s_barrier();
    gateStage(ho, R5_BOFF, accR);
    __builtin_amdgcn_s_barrier();
    if (f < 15) {
      stageB(0, f + 1, R5_BOFF);
      asm volatile("s_waitcnt vmcnt(4)" ::: "memory");
    } else {
      asm volatile("s_waitcnt vmcnt(0)" ::: "memory");
    }
    __builtin_amdgcn_s_barrier();
    gateStage(ho, R5_BOFF + 32768, accZ);
    __builtin_amdgcn_s_barrier();
  }

#pragma unroll
  for (int cf = 0; cf < 4; ++cf) {
    const int col  = (cfg0 + cf) * 16 + lr;
    const float bs = b_rx[col] + b_rh[col];
    const int fcol  = col >> 5;
    const int l2b   = ((col >> 3) & 3) * 16;
    const int ebyte = (col & 7) * 2;
#pragma unroll
    for (int rf = 0; rf < 4; ++rf) {
#pragma unroll
      for (int j = 0; j < 4; ++j) {
        const int rsub = lk * 4 + j;
        unsigned short hu = *(const unsigned short*)
            &lds[fcol * 4096 + rf * 1024 + (l2b + rsub) * 16 + ebyte];
        float rv = sigmoid_fast(accR[rf][cf][j] + bs);
        *(unsigned short*)
            &lds[R5_BOFF + fcol * 4096 + rf * 1024 + (l2b + rsub) * 16 + ebyte]
            = f2bf(rv * bf2f(hu));
      }
    }
  }
  __syncthreads();

  f32x4 accN[4][4] = {};
  stageXpair(0);
  stageB(4, 0, 0);
#pragma unroll 1
  for (int f = 0; f < 16; ++f) {
    const int xo = R5_XOFF + ((f >> 1) & 1) * 8192 + (f & 1) * 4096;
    stageB(5, f, 32768);
    if (f & 1) {
      int p1 = (f >> 1) + 1; if (p1 > 7) p1 = 7;
      stageXpair(p1);
      asm volatile("s_waitcnt vmcnt(5)" ::: "memory");
    } else {
      asm volatile("s_waitcnt vmcnt(4)" ::: "memory");
    }
    __builtin_amdgcn_s_barrier();
    gateStage(xo, 0, accN);
    __builtin_amdgcn_s_barrier();
    if (f < 15) {
      stageB(4, f + 1, 0);
      asm volatile("s_waitcnt vmcnt(4)" ::: "memory");
    } else {
      asm volatile("s_waitcnt vmcnt(0)" ::: "memory");
    }
    __builtin_amdgcn_s_barrier();
    gateStage(R5_BOFF + f * 4096, 32768, accN);
    __builtin_amdgcn_s_barrier();
  }

#pragma unroll
  for (int cf = 0; cf < 4; ++cf) {
    const int col  = (cfg0 + cf) * 16 + lr;
    const float bn = b_nx[col] + b_nh[col];
    const float bz = b_zx[col] + b_zh[col];
#pragma unroll
    for (int rf = 0; rf < 4; ++rf) {
#pragma unroll
      for (int j = 0; j < 4; ++j) {
        const int row = rf * 16 + lk * 4 + j;
        const size_t off = (size_t)(row0 + row) * DIM + col;
        float hv = h[off];
        float nv = tanh_fast(accN[rf][cf][j] + bn);
        float zv = sigmoid_fast(accZ[rf][cf][j] + bz);
        out[off] = (1.0f - zv) * nv + zv * hv;
      }
    }
  }
}

extern "C" void kernel_launch(void* const* d_in, const int* in_sizes, int n_in,
                              void* d_out, int out_size, void* d_ws, size_t ws_size,
                              hipStream_t stream) {
  const float* x    = (const float*)d_in[0];
  const float* h    = (const float*)d_in[1];
  const float* W_rx = (const float*)d_in[2];
  const float* b_rx = (const float*)d_in[3];
  const float* W_rh = (const float*)d_in[4];
  const float* b_rh = (const float*)d_in[5];
  const float* W_zx = (const float*)d_in[6];
  const float* b_zx = (const float*)d_in[7];
  const float* W_zh = (const float*)d_in[8];
  const float* b_zh = (const float*)d_in[9];
  const float* W_nx = (const float*)d_in[10];
  const float* b_nx = (const float*)d_in[11];
  const float* W_nh = (const float*)d_in[12];
  const float* b_nh = (const float*)d_in[13];

  unsigned char* ws = (unsigned char*)d_ws;
  unsigned short* wpack = (unsigned short*)ws;                  // 3 MiB
  const size_t SEG = (size_t)NROWS * DIM * 2;                   // 128 MiB
  const size_t xb_off  = 4ull << 20;
  const size_t hb_off  = xb_off + SEG;
  const size_t rhb_off = hb_off + SEG;
  const size_t zb_off  = rhb_off + SEG;
  const size_t need_main = zb_off;          // 388 MiB (z -> d_out fp32)
  const size_t need_zb   = zb_off + SEG;    // 516 MiB (z -> bf16 ws)

  // gate order: rx, zx, rh, zh, nx, nh
  prepack_weights<<<6144, 256, 0, stream>>>(W_rx, W_zx, W_rh, W_zh, W_nx, W_nh, wpack);

  if (ws_size >= need_main) {
    unsigned short* xb  = (unsigned short*)(ws + xb_off);
    unsigned short* hb  = (unsigned short*)(ws + hb_off);
    unsigned short* rhb = (unsigned short*)(ws + rhb_off);
    unsigned short* zb  = (ws_size >= need_zb) ? (unsigned short*)(ws + zb_off)
                                               : (unsigned short*)nullptr;
    prep_bf16<<<32768, 256, 0, stream>>>(x, xb);
    prep_bf16<<<32768, 256, 0, stream>>>(h, hb);
    gru_3sweep<<<NROWS / 64, 256, 0, stream>>>(h, xb, hb, rhb, zb,
                                               (const unsigned char*)wpack,
                                               b_rx, b_rh, b_zx, b_zh, b_nx, b_nh,
                                               (float*)d_out);
  } else {
    unsigned short* xb = (unsigned short*)(ws + xb_off);        // 132 MiB proven
    prep_bf16<<<32768, 256, 0, stream>>>(x, xb);
    gru_fused_r5<<<NROWS / 64, 512, 0, stream>>>(h, xb,
                                                 (const unsigned char*)wpack,
                                                 b_rx, b_rh, b_zx, b_zh, b_nx, b_nh,
                                                 (float*)d_out);
  }
}

// Round 12
// 722.800 us; speedup vs baseline: 2.1535x; 2.1535x over previous
//
#include <hip/hip_runtime.h>

#define DIM 512
#define NROWS 131072

typedef __attribute__((ext_vector_type(8))) __bf16 bf16x8;
typedef __attribute__((ext_vector_type(4))) float f32x4;

__device__ __forceinline__ unsigned short f2bf(float f) {
  unsigned u = __builtin_bit_cast(unsigned, f);
  return (unsigned short)((u + 0x7FFFu + ((u >> 16) & 1u)) >> 16);
}
__device__ __forceinline__ float bf2f(unsigned short u) {
  return __builtin_bit_cast(float, (unsigned)u << 16);
}
__device__ __forceinline__ f32x4 mfma16(bf16x8 a, bf16x8 b, f32x4 c) {
  return __builtin_amdgcn_mfma_f32_16x16x32_bf16(a, b, c, 0, 0, 0);
}
__device__ __forceinline__ float sigmoid_fast(float v) {
  return 1.0f / (1.0f + __expf(-v));
}
__device__ __forceinline__ float tanh_fast(float v) {
  float e = __expf(2.0f * v);
  return 1.0f - 2.0f / (e + 1.0f);
}
__device__ __forceinline__ void gl2lds(const void* g, void* l) {
  __builtin_amdgcn_global_load_lds(
      (const __attribute__((address_space(1))) unsigned int*)g,
      (__attribute__((address_space(3))) unsigned int*)l, 16, 0, 0);
}

// ---------------------------------------------------------------------------
// Weight pre-pack: fp32 W[out=512][in=512] -> bf16 B-fragments.
// Frag (gate g, kstep f, colfrag c): lane l holds 8 bf16 =
//   W[c*16 + (l&15)][f*32 + (l>>4)*8 + 0..7]
// elem index = ((g*16+f)*32 + c)*512 + l*8 + e.  Gates: rx,zx,rh,zh,nx,nh.
// ---------------------------------------------------------------------------
__global__ void prepack_weights(const float* __restrict__ W0, const float* __restrict__ W1,
                                const float* __restrict__ W2, const float* __restrict__ W3,
                                const float* __restrict__ W4, const float* __restrict__ W5,
                                unsigned short* __restrict__ out) {
  int idx = blockIdx.x * 256 + threadIdx.x;
  int e = idx & 7;
  int l = (idx >> 3) & 63;
  int c = (idx >> 9) & 31;
  int f = (idx >> 14) & 15;
  int g = idx >> 18;
  const float* W = (g == 0) ? W0 : (g == 1) ? W1 : (g == 2) ? W2
                 : (g == 3) ? W3 : (g == 4) ? W4 : W5;
  int row = c * 16 + (l & 15);
  int kk  = f * 32 + ((l >> 4) << 3) + e;
  out[idx] = f2bf(W[row * DIM + kk]);
}

// x -> bf16 row-major (async gl2lds A-staging source)
__global__ void prep_x(const float* __restrict__ x, unsigned short* __restrict__ xb) {
  size_t i = (size_t)(blockIdx.x * 256 + threadIdx.x) * 8;
  float4 a0 = *(const float4*)(x + i);
  float4 a1 = *(const float4*)(x + i + 4);
  union { unsigned short us[8]; uint4 v; } p;
  p.us[0] = f2bf(a0.x); p.us[1] = f2bf(a0.y); p.us[2] = f2bf(a0.z); p.us[3] = f2bf(a0.w);
  p.us[4] = f2bf(a1.x); p.us[5] = f2bf(a1.y); p.us[6] = f2bf(a1.z); p.us[7] = f2bf(a1.w);
  *(uint4*)(xb + i) = p.v;
}

// h -> bf16 frag-panel layout: hfb[panel][f16][rf4][lane64][8]
//   row = panel*64 + rf*16 + (lane&15), k = f*32 + (lane>>4)*8 + e
__global__ void prep_h(const float* __restrict__ h, unsigned short* __restrict__ hfb) {
  size_t idx  = (size_t)(blockIdx.x * 256 + threadIdx.x);
  size_t base = idx * 8;
  size_t panel = base >> 15;
  int rem  = (int)(base & 32767);
  int f    = rem >> 11;
  int rf   = (rem >> 9) & 3;
  int lane = (rem >> 3) & 63;
  int row  = (int)panel * 64 + rf * 16 + (lane & 15);
  int k    = f * 32 + (lane >> 4) * 8;
  const float* src = h + (size_t)row * DIM + k;
  float4 a0 = *(const float4*)src;
  float4 a1 = *(const float4*)(src + 4);
  union { unsigned short us[8]; uint4 v; } p;
  p.us[0] = f2bf(a0.x); p.us[1] = f2bf(a0.y); p.us[2] = f2bf(a0.z); p.us[3] = f2bf(a0.w);
  p.us[4] = f2bf(a1.x); p.us[5] = f2bf(a1.y); p.us[6] = f2bf(a1.z); p.us[7] = f2bf(a1.w);
  *(uint4*)(hfb + base) = p.v;
}

// LDS map (bytes):
//   [0, 64K)       sweep1: h frags [f16][rf4][lane][16B]; becomes rh frags
//   [64K, 128K)    B dbuf 2x32K
//   [128K, 144K)   x dbuf 2x8K  [pair][f&1][rf4][lane][16B]
#define BOFF 65536
#define XOFF 131072
#define LDS_BYTES 147456

// ---------------------------------------------------------------------------
// Fused GRU (R5 structure + A-pair register reuse + gl2lds h prologue).
// Block = 64r x 512c, 8 waves, wave = 64r x 64c, 16 MFMA/window.
// Window = {issue stage; vmcnt(N); s_barrier; ds_read; MFMA; s_barrier}.
// rx/zx windows share one x(f) A-frag read; rh/zh share one h(f) read
// (single shared af[4] buffer -> no added register pressure).
// ---------------------------------------------------------------------------
__global__ __launch_bounds__(512, 1)
void gru_fused(const float* __restrict__ h,
               const unsigned short* __restrict__ xb,
               const unsigned short* __restrict__ hfb,   // frag-panel bf16 h (or null)
               const unsigned char* __restrict__ WB,
               const float* __restrict__ b_rx, const float* __restrict__ b_rh,
               const float* __restrict__ b_zx, const float* __restrict__ b_zh,
               const float* __restrict__ b_nx, const float* __restrict__ b_nh,
               float* __restrict__ out) {
  __shared__ __align__(1024) unsigned char lds[LDS_BYTES];

  const int tid  = threadIdx.x;
  const int lane = tid & 63;
  const int w    = tid >> 6;
  const int cfg0 = w * 4;
  const int row0 = blockIdx.x * 64;
  const int lr   = lane & 15;
  const int lk   = lane >> 4;

  bf16x8 af[4], bfr[4];

  auto stageB = [&](int g, int f, int dst) {   // 32KB chunk, 4 gl2lds/thread
    const unsigned char* src = WB + (size_t)(g * 16 + f) * 32768;
#pragma unroll
    for (int it = 0; it < 4; ++it) {
      int o = (it * 512 + tid) * 16;
      gl2lds(src + o, &lds[dst + o]);
    }
  };
  auto stageXpair = [&](int p) {               // 8KB: k-steps {2p,2p+1}
    int fh = tid >> 8, rf = (tid >> 6) & 3, l = tid & 63;
    const unsigned short* src = xb + (size_t)(row0 + rf * 16 + (l & 15)) * DIM
                                + p * 64 + fh * 32 + (l >> 4) * 8;
    gl2lds(src, &lds[XOFF + (p & 1) * 8192 + tid * 16]);
  };
  auto readA4 = [&](int abase) {
#pragma unroll
    for (int rf = 0; rf < 4; ++rf)
      af[rf] = *(const bf16x8*)&lds[abase + rf * 1024 + lane * 16];
  };
  auto readB4 = [&](int bbase) {
#pragma unroll
    for (int cf = 0; cf < 4; ++cf)
      bfr[cf] = *(const bf16x8*)&lds[bbase + (cfg0 + cf) * 1024 + lane * 16];
  };

#define DOMFMA(ACC)                                                            \
  do {                                                                         \
    _Pragma("unroll")                                                          \
    for (int rf_ = 0; rf_ < 4; ++rf_)                                          \
      _Pragma("unroll")                                                        \
      for (int cf_ = 0; cf_ < 4; ++cf_)                                        \
        ACC[rf_][cf_] = mfma16(af[rf_], bfr[cf_], ACC[rf_][cf_]);              \
  } while (0)

  f32x4 accR[4][4] = {}, accZ[4][4] = {};

  // ---- prologue: h frags -> LDS (gl2lds if hfb), x pair0, rx0 ----
  if (hfb) {
    const unsigned char* src = (const unsigned char*)(hfb + (size_t)blockIdx.x * 32768);
#pragma unroll
    for (int it = 0; it < 8; ++it) {
      int o = (it * 512 + tid) * 16;
      gl2lds(src + o, &lds[o]);
    }
  } else {
#pragma unroll
    for (int it = 0; it < 16; ++it) {
      int i = tid + it * 512;
      int row = i >> 7;
      int k = (i & 127) * 4;
      float4 hv4 = *(const float4*)(h + (size_t)(row0 + row) * DIM + k);
      union { unsigned short us[4]; uint2 v; } p;
      p.us[0] = f2bf(hv4.x); p.us[1] = f2bf(hv4.y);
      p.us[2] = f2bf(hv4.z); p.us[3] = f2bf(hv4.w);
      *(uint2*)&lds[(k >> 5) * 4096 + (row >> 4) * 1024
                    + (((k >> 3) & 3) * 16 + (row & 15)) * 16 + (k & 4) * 2] = p.v;
    }
  }
  stageXpair(0);
  stageB(0, 0, BOFF);                 // rx0 -> b0
  __syncthreads();                    // one full drain; pipeline starts clean

  // ---- sweep 1: f x {rx, zx, rh, zh}; counted vmcnt, raw barriers ----
#pragma unroll 1
  for (int f = 0; f < 16; ++f) {
    const int xo = XOFF + ((f >> 1) & 1) * 8192 + (f & 1) * 4096;
    const int ho = f * 4096;
    // W0: compute rx(f)@b0 (read x frags); stage zx(f)->b1 (+ x pair on odd f)
    stageB(1, f, BOFF + 32768);
    if (f & 1) {
      int p1 = (f >> 1) + 1; if (p1 > 7) p1 = 7;
      stageXpair(p1);
      asm volatile("s_waitcnt vmcnt(5)" ::: "memory");
    } else {
      asm volatile("s_waitcnt vmcnt(4)" ::: "memory");
    }
    __builtin_amdgcn_s_barrier();
    readA4(xo);
    readB4(BOFF);
    DOMFMA(accR);
    __builtin_amdgcn_s_barrier();
    // W1: compute zx(f)@b1 (reuse x frags); stage rh(f)->b0
    stageB(2, f, BOFF);
    asm volatile("s_waitcnt vmcnt(4)" ::: "memory");
    __builtin_amdgcn_s_barrier();
    readB4(BOFF + 32768);
    DOMFMA(accZ);
    __builtin_amdgcn_s_barrier();
    // W2: compute rh(f)@b0 (read h frags); stage zh(f)->b1
    stageB(3, f, BOFF + 32768);
    asm volatile("s_waitcnt vmcnt(4)" ::: "memory");
    __builtin_amdgcn_s_barrier();
    readA4(ho);
    readB4(BOFF);
    DOMFMA(accR);
    __builtin_amdgcn_s_barrier();
    // W3: compute zh(f)@b1 (reuse h frags); stage rx(f+1)->b0
    if (f < 15) {
      stageB(0, f + 1, BOFF);
      asm volatile("s_waitcnt vmcnt(4)" ::: "memory");
    } else {
      asm volatile("s_waitcnt vmcnt(0)" ::: "memory");
    }
    __builtin_amdgcn_s_barrier();
    readB4(BOFF + 32768);
    DOMFMA(accZ);
    __builtin_amdgcn_s_barrier();
  }

  // ---- r-epilogue: r = sigmoid(accR+b); rh = r*h in place in frag LDS ----
#pragma unroll
  for (int cf = 0; cf < 4; ++cf) {
    const int col  = (cfg0 + cf) * 16 + lr;
    const float bs = b_rx[col] + b_rh[col];
    const int fcol  = col >> 5;
    const int l2b   = ((col >> 3) & 3) * 16;
    const int ebyte = (col & 7) * 2;
#pragma unroll
    for (int rf = 0; rf < 4; ++rf) {
#pragma unroll
      for (int j = 0; j < 4; ++j) {
        const int rsub = lk * 4 + j;
        const int addr = fcol * 4096 + rf * 1024 + (l2b + rsub) * 16 + ebyte;
        unsigned short hu = *(const unsigned short*)&lds[addr];
        float rv = sigmoid_fast(accR[rf][cf][j] + bs);
        *(unsigned short*)&lds[addr] = f2bf(rv * bf2f(hu));
      }
    }
  }
  __syncthreads();                    // rh visible

  // ---- sweep 2: f x {nx, nh}; B dbuf @BOFF; A(nh) = rh frags @[0,64K) ----
  f32x4 accN[4][4] = {};
  stageXpair(0);
  stageB(4, 0, BOFF);                 // nx0 -> b0 (5 loads in flight)
#pragma unroll 1
  for (int f = 0; f < 16; ++f) {
    const int xo = XOFF + ((f >> 1) & 1) * 8192 + (f & 1) * 4096;
    // V0: compute nx(f)@b0; stage nh(f)->b1 (+ x pair on odd f)
    stageB(5, f, BOFF + 32768);
    if (f & 1) {
      int p1 = (f >> 1) + 1; if (p1 > 7) p1 = 7;
      stageXpair(p1);
      asm volatile("s_waitcnt vmcnt(5)" ::: "memory");
    } else {
      asm volatile("s_waitcnt vmcnt(4)" ::: "memory");
    }
    __builtin_amdgcn_s_barrier();
    readA4(xo);
    readB4(BOFF);
    DOMFMA(accN);
    __builtin_amdgcn_s_barrier();
    // V1: compute nh(f)@b1 (A = rh frags); stage nx(f+1)->b0
    if (f < 15) {
      stageB(4, f + 1, BOFF);
      asm volatile("s_waitcnt vmcnt(4)" ::: "memory");
    } else {
      asm volatile("s_waitcnt vmcnt(0)" ::: "memory");
    }
    __builtin_amdgcn_s_barrier();
    readA4(f * 4096);
    readB4(BOFF + 32768);
    DOMFMA(accN);
    __builtin_amdgcn_s_barrier();
  }

  // ---- final epilogue: n = tanh(accN+b), z = sigmoid(accZ+b), combine ----
#pragma unroll
  for (int cf = 0; cf < 4; ++cf) {
    const int col  = (cfg0 + cf) * 16 + lr;
    const float bn = b_nx[col] + b_nh[col];
    const float bz = b_zx[col] + b_zh[col];
#pragma unroll
    for (int rf = 0; rf < 4; ++rf) {
#pragma unroll
      for (int j = 0; j < 4; ++j) {
        const int row = rf * 16 + lk * 4 + j;
        const size_t off = (size_t)(row0 + row) * DIM + col;
        float hv = h[off];
        float nv = tanh_fast(accN[rf][cf][j] + bn);
        float zv = sigmoid_fast(accZ[rf][cf][j] + bz);
        out[off] = (1.0f - zv) * nv + zv * hv;
      }
    }
  }
#undef DOMFMA
}

extern "C" void kernel_launch(void* const* d_in, const int* in_sizes, int n_in,
                              void* d_out, int out_size, void* d_ws, size_t ws_size,
                              hipStream_t stream) {
  const float* x    = (const float*)d_in[0];
  const float* h    = (const float*)d_in[1];
  const float* W_rx = (const float*)d_in[2];
  const float* b_rx = (const float*)d_in[3];
  const float* W_rh = (const float*)d_in[4];
  const float* b_rh = (const float*)d_in[5];
  const float* W_zx = (const float*)d_in[6];
  const float* b_zx = (const float*)d_in[7];
  const float* W_zh = (const float*)d_in[8];
  const float* b_zh = (const float*)d_in[9];
  const float* W_nx = (const float*)d_in[10];
  const float* b_nx = (const float*)d_in[11];
  const float* W_nh = (const float*)d_in[12];
  const float* b_nh = (const float*)d_in[13];

  unsigned char* ws = (unsigned char*)d_ws;
  unsigned short* wpack = (unsigned short*)ws;                  // 3 MiB
  const size_t SEG = (size_t)NROWS * DIM * 2;                   // 128 MiB
  unsigned short* xb = (unsigned short*)(ws + (4ull << 20));    // proven fits
  const size_t hfb_off = (4ull << 20) + SEG;
  unsigned short* hfb = (ws_size >= hfb_off + SEG)
                        ? (unsigned short*)(ws + hfb_off)
                        : (unsigned short*)nullptr;

  // gate order: rx, zx, rh, zh, nx, nh
  prepack_weights<<<6144, 256, 0, stream>>>(W_rx, W_zx, W_rh, W_zh, W_nx, W_nh, wpack);
  prep_x<<<32768, 256, 0, stream>>>(x, xb);
  if (hfb) prep_h<<<32768, 256, 0, stream>>>(h, hfb);
  gru_fused<<<NROWS / 64, 512, 0, stream>>>(h, xb, hfb, (const unsigned char*)wpack,
                                            b_rx, b_rh, b_zx, b_zh, b_nx, b_nh,
                                            (float*)d_out);
}